// Round 8
// baseline (94.674 us; speedup 1.0000x reference)
//
#include <hip/hip_runtime.h>
#include <math.h>

// Problem constants (B=1)
#define T 2048
#define C 1024
#define H 16
#define HD 64
#define N3 (3*C)
#define NBLOCK 2048

typedef __attribute__((ext_vector_type(8))) short bf16x8;
typedef __attribute__((ext_vector_type(4))) float f32x4;

#define MFMA16(a, b, c) __builtin_amdgcn_mfma_f32_16x16x32_bf16((a), (b), (c), 0, 0, 0)

__device__ inline short f2bf(float f) {
    unsigned u; __builtin_memcpy(&u, &f, 4);
    unsigned r = (u + 0x7fffu + ((u >> 16) & 1u)) >> 16;
    return (short)r;
}
__device__ inline float bf2f(short s) {
    unsigned u = ((unsigned)(unsigned short)s) << 16;
    float f; __builtin_memcpy(&f, &u, 4);
    return f;
}

// async global->LDS, 16B per lane. lds base must be wave-uniform; HW adds lane*16.
__device__ inline void gload_lds16(const void* g, void* l) {
    __builtin_amdgcn_global_load_lds((const __attribute__((address_space(1))) unsigned int*)g,
                                     (__attribute__((address_space(3))) unsigned int*)l,
                                     16, 0, 0);
}

// ---------------- merged: conv x + weight transposes + (block 3072) prep + sincos table ----------------
__global__ __launch_bounds__(256) void pre_kernel(const float* __restrict__ x,
                                                  const float* __restrict__ w_attn,
                                                  const float* __restrict__ w_proj,
                                                  const int* __restrict__ tok,
                                                  const float* __restrict__ padmask,
                                                  short* __restrict__ xb,
                                                  short* __restrict__ wabT,
                                                  short* __restrict__ wpbT,
                                                  float2* __restrict__ tab,
                                                  float* __restrict__ pm_tok) {
    int bid = blockIdx.x;
    int tid = threadIdx.x;
    if (bid == 3072) {
        // histogram + scan + pm gather + cos/sin table (single block)
        __shared__ float cntS[NBLOCK];
        __shared__ float sums[256];
        #pragma unroll
        for (int j = 0; j < 8; ++j) cntS[tid * 8 + j] = 0.0f;
        __syncthreads();
        int tk[8];
        #pragma unroll
        for (int j = 0; j < 8; ++j) {
            tk[j] = tok[tid * 8 + j];
            atomicAdd(&cntS[tk[j]], 1.0f);
        }
        __syncthreads();
        float vals[8];
        float s = 0.0f;
        #pragma unroll
        for (int j = 0; j < 8; ++j) {
            s += 1.0f / (cntS[tk[j]] + 1e-10f);
            vals[j] = s;
            pm_tok[tid * 8 + j] = padmask[tk[j]];
        }
        sums[tid] = s;
        __syncthreads();
        for (int off = 1; off < 256; off <<= 1) {
            float v = (tid >= off) ? sums[tid - off] : 0.0f;
            __syncthreads();
            sums[tid] += v;
            __syncthreads();
        }
        float offset = (tid > 0) ? sums[tid - 1] : 0.0f;
        // cos/sin table: thread owns t = tid*8+e, its partial = offset + vals[e]
        float invf[32];
        #pragma unroll
        for (int j = 0; j < 32; ++j)
            invf[j] = exp2f(-(float)j * (13.287712379549449f / 32.0f));  // 10000^(-j/32)
        #pragma unroll
        for (int e = 0; e < 8; ++e) {
            float p = offset + vals[e];
            float2* row = tab + (tid * 8 + e) * 32;
            #pragma unroll
            for (int j = 0; j < 32; ++j) {
                float s_, c_;
                __sincosf(p * invf[j], &s_, &c_);
                row[j] = make_float2(c_, s_);
            }
        }
        return;
    }
    if (bid < 2048) {
        int i = bid * 1024 + tid * 4;
        float4 v = *(const float4*)(x + i);
        short4 o;
        o.x = f2bf(v.x); o.y = f2bf(v.y); o.z = f2bf(v.z); o.w = f2bf(v.w);
        *(short4*)(xb + i) = o;
        return;
    }
    __shared__ float S[64][65];
    const float* in; short* out; int Kd, Nd, bx, by;
    if (bid < 2816) {
        int b = bid - 2048;              // (48, 16)
        bx = b % 48; by = b / 48;
        in = w_attn; out = wabT; Kd = C; Nd = N3;
    } else {
        int b = bid - 2816;              // (16, 16)
        bx = b % 16; by = b / 16;
        in = w_proj; out = wpbT; Kd = C; Nd = C;
    }
    int n0 = bx * 64, k0 = by * 64;
    #pragma unroll
    for (int i = 0; i < 16; ++i) {
        int lin = tid + i * 256;
        int r = lin >> 6, c = lin & 63;
        S[r][c] = in[(size_t)(k0 + r) * Nd + n0 + c];
    }
    __syncthreads();
    #pragma unroll
    for (int i = 0; i < 16; ++i) {
        int lin = tid + i * 256;
        int rn = lin >> 6, ck = lin & 63;
        out[(size_t)(n0 + rn) * Kd + k0 + ck] = f2bf(S[ck][rn]);
    }
}

// ---------------- bf16 GEMM 128x64 tile, BK=64, m-split waves, XOR-swizzled LDS ----------------
// EPI=0: f32 out + bias (proj). EPI=1: fused qkv epilogue (rope q/k + fixups; v scaled+transposed).
// LDS rows are 128B -> 32-way conflict unless swizzled: store with pre-swizzled GLOBAL src col
// (gload_lds dest is linear), read with the same XOR (involution), per rule #21.
template <int EPI>
__global__ __launch_bounds__(256) void gemm128x64(const short* __restrict__ A,
                                                  const short* __restrict__ Bt,
                                                  const float* __restrict__ bias,
                                                  void* __restrict__ Cout,
                                                  int N, int K,
                                                  const float2* __restrict__ tab,
                                                  const float* __restrict__ cumsc,
                                                  const float* __restrict__ pm_tok,
                                                  short* __restrict__ vbT) {
    __shared__ alignas(16) short As[2][128 * 64];
    __shared__ alignas(16) short Bs[2][64 * 64];
    int tid = threadIdx.x;
    int m0 = blockIdx.y * 128, n0 = blockIdx.x * 64;
    int w = tid >> 6, l = tid & 63;
    int lq = l & 15, g = l >> 4;
    int urow = l >> 3;                       // 0..7 within a 1KB (8row x 64col) unit
    int sw_col = ((l & 7) ^ urow) * 8;       // pre-swizzled source column (shorts)

    f32x4 acc[2][4] = {};

    auto stage = [&](int buf, int k0) {
        #pragma unroll
        for (int i = 0; i < 4; ++i) {
            int u = w * 4 + i;
            gload_lds16(A + (size_t)(m0 + u * 8 + urow) * K + k0 + sw_col, As[buf] + u * 512);
        }
        #pragma unroll
        for (int i = 0; i < 2; ++i) {
            int u = w * 2 + i;
            gload_lds16(Bt + (size_t)(n0 + u * 8 + urow) * K + k0 + sw_col, Bs[buf] + u * 512);
        }
    };

    int NK = K / 64;
    stage(0, 0);
    asm volatile("s_waitcnt vmcnt(0)" ::: "memory");
    __builtin_amdgcn_s_barrier();
    __builtin_amdgcn_sched_barrier(0);

    for (int t = 0; t < NK; ++t) {
        int cur = t & 1;
        if (t + 1 < NK) stage(cur ^ 1, (t + 1) * 64);
        #pragma unroll
        for (int kk = 0; kk < 2; ++kk) {
            bf16x8 af[2], bfr[4];
            #pragma unroll
            for (int fi = 0; fi < 2; ++fi) {
                int rd = w * 32 + fi * 16 + lq;
                af[fi] = *(const bf16x8*)(As[cur] + rd * 64 + (((kk * 4 + g) ^ (rd & 7)) * 8));
            }
            #pragma unroll
            for (int fj = 0; fj < 4; ++fj) {
                int rd = fj * 16 + lq;
                bfr[fj] = *(const bf16x8*)(Bs[cur] + rd * 64 + (((kk * 4 + g) ^ (rd & 7)) * 8));
            }
            __builtin_amdgcn_s_setprio(1);
            #pragma unroll
            for (int fi = 0; fi < 2; ++fi)
                #pragma unroll
                for (int fj = 0; fj < 4; ++fj)
                    acc[fi][fj] = MFMA16(af[fi], bfr[fj], acc[fi][fj]);
            __builtin_amdgcn_s_setprio(0);
        }
        asm volatile("s_waitcnt vmcnt(0)" ::: "memory");
        __builtin_amdgcn_s_barrier();
        __builtin_amdgcn_sched_barrier(0);
    }

    if (EPI == 0) {
        float* Cf = (float*)Cout;
        #pragma unroll
        for (int fi = 0; fi < 2; ++fi)
            #pragma unroll
            for (int r = 0; r < 4; ++r) {
                int m = m0 + w * 32 + fi * 16 + g * 4 + r;
                #pragma unroll
                for (int fj = 0; fj < 4; ++fj) {
                    int n = n0 + fj * 16 + lq;
                    Cf[(size_t)m * N + n] = acc[fi][fj][r] + bias[n];
                }
            }
    } else {
        short* Cb = (short*)Cout;   // qkvb
        int nt = n0 >> 6;           // 0..15 q, 16..31 k, 32..47 v
        if (nt < 32) {
            bool isQ = (nt < 16);
            #pragma unroll
            for (int fi = 0; fi < 2; ++fi)
                #pragma unroll
                for (int r = 0; r < 4; ++r) {
                    int trow = m0 + w * 32 + fi * 16 + g * 4 + r;
                    float pm = pm_tok[trow];
                    float csc = cumsc[trow];
                    float2 cs0 = tab[trow * 32 + lq];
                    float2 cs1 = tab[trow * 32 + 16 + lq];
                    float a0 = acc[fi][0][r] + bias[n0 + lq];
                    float a1 = acc[fi][1][r] + bias[n0 + 16 + lq];
                    float a2 = acc[fi][2][r] + bias[n0 + 32 + lq];
                    float a3 = acc[fi][3][r] + bias[n0 + 48 + lq];
                    float lo0 = a0 * cs0.x - a2 * cs0.y;
                    float hi0 = a2 * cs0.x + a0 * cs0.y;
                    float lo1 = a1 * cs1.x - a3 * cs1.y;
                    float hi1 = a3 * cs1.x + a1 * cs1.y;
                    if (lq == 15)   // j == 31 -> d == 63 fixups (padding folded in)
                        hi1 = isQ ? ((pm != 0.0f) ? 1.0f : 0.0f)
                                  : ((pm != 0.0f) ? csc : -1e20f);
                    size_t base = (size_t)trow * N3 + n0;
                    Cb[base + lq]      = f2bf(lo0);
                    Cb[base + 16 + lq] = f2bf(lo1);
                    Cb[base + 32 + lq] = f2bf(hi0);
                    Cb[base + 48 + lq] = f2bf(hi1);
                }
        } else {
            int h = nt - 32;
            short* Sv = &As[0][0];            // reuse 17.4KB of As as Sv[64][136]
            __syncthreads();
            #pragma unroll
            for (int fi = 0; fi < 2; ++fi)
                #pragma unroll
                for (int r = 0; r < 4; ++r) {
                    int tloc = w * 32 + fi * 16 + g * 4 + r;
                    float ef = __expf(cumsc[m0 + tloc]);
                    #pragma unroll
                    for (int fj = 0; fj < 4; ++fj) {
                        int d = fj * 16 + lq;
                        Sv[d * 136 + tloc] = f2bf((acc[fi][fj][r] + bias[n0 + d]) * ef);
                    }
                }
            __syncthreads();
            #pragma unroll
            for (int e = 0; e < 4; ++e) {
                int idx = tid * 4 + e;
                int d = idx >> 4, t8 = (idx & 15) * 8;
                bf16x8 o = *(const bf16x8*)(Sv + d * 136 + t8);
                *(bf16x8*)(vbT + (size_t)(h * 64 + d) * T + m0 + t8) = o;
            }
        }
    }
}

// ---------------- MFMA flash attention: staged dbuf + streaming softmax + paired balance ----------------
// 512 blocks. Pair (b, b+256) -> same XCD (256%8==0): work sums to 33 tiles.
__global__ __launch_bounds__(256) void attn_flash(const short* __restrict__ qkvb,
                                                  const short* __restrict__ vbT,
                                                  short* __restrict__ yb) {
    __shared__ alignas(16) short Kt[2][64 * 64];      // [k][d], XOR-swizzled rows
    __shared__ alignas(16) short Vt[2][64 * 64];      // [d][k], XOR-swizzled rows
    __shared__ alignas(16) short Ps[4][16][72];       // wave-private P[q][k]

    int b = blockIdx.x;
    int h, qt;
    if (b < 256) { h = b & 15; qt = 31 - (b >> 4); }
    else         { int c2 = b - 256; h = c2 & 15; qt = c2 >> 4; }
    int tid = threadIdx.x;
    int w = tid >> 6, l = tid & 63;
    int lq = l & 15, g = l >> 4;
    int qrl = w * 16 + lq;

    const short* qbase = qkvb + (size_t)(qt * 64 + qrl) * N3 + h * 64;
    bf16x8 qf0 = *(const bf16x8*)(qbase + g * 8);
    bf16x8 qf1 = *(const bf16x8*)(qbase + 32 + g * 8);

    f32x4 accO[4] = {};
    float lsum = 0.0f;

    int srow = tid >> 3, scol = (tid & 7) * 8;
    const short* kgb = qkvb + C + h * 64 + scol;
    const short* vgb = vbT + (size_t)(h * 64) * T + scol;
    int wb0 = srow * 128 + ((scol * 2) ^ ((srow & 7) << 4));
    int wb1 = (srow + 32) * 128 + ((scol * 2) ^ ((srow & 7) << 4));

    auto do_tile = [&](int cur, bool masked) {
        const char* Kc = (const char*)Kt[cur];
        const char* Vc = (const char*)Vt[cur];
        f32x4 s[4] = {};
        __builtin_amdgcn_s_setprio(1);
        #pragma unroll
        for (int f = 0; f < 4; ++f) {
            int row = f * 16 + lq;
            const char* kr_ = Kc + row * 128;
            int sw = (row & 7) << 4;
            bf16x8 a0 = *(const bf16x8*)(kr_ + ((g * 16) ^ sw));
            bf16x8 a1 = *(const bf16x8*)(kr_ + ((64 + g * 16) ^ sw));
            s[f] = MFMA16(a0, qf0, s[f]);
            s[f] = MFMA16(a1, qf1, s[f]);
        }
        __builtin_amdgcn_s_setprio(0);
        float p[16];
        #pragma unroll
        for (int f = 0; f < 4; ++f)
            #pragma unroll
            for (int r = 0; r < 4; ++r) {
                float sv = s[f][r] * 0.125f;
                if (masked) {
                    int kl = f * 16 + g * 4 + r;
                    sv = (kl > qrl) ? -INFINITY : sv;
                }
                float pv = __expf(sv);
                p[f * 4 + r] = pv;
                lsum += pv;
            }
        #pragma unroll
        for (int f = 0; f < 4; ++f) {
            unsigned u0, u1;
            asm("v_cvt_pk_bf16_f32 %0, %1, %2" : "=v"(u0) : "v"(p[f * 4 + 0]), "v"(p[f * 4 + 1]));
            asm("v_cvt_pk_bf16_f32 %0, %1, %2" : "=v"(u1) : "v"(p[f * 4 + 2]), "v"(p[f * 4 + 3]));
            uint2 uu; uu.x = u0; uu.y = u1;
            *(uint2*)&Ps[w][lq][f * 16 + g * 4] = uu;
        }
        __builtin_amdgcn_s_setprio(1);
        #pragma unroll
        for (int kh = 0; kh < 2; ++kh) {
            bf16x8 pa = *(const bf16x8*)&Ps[w][lq][kh * 32 + g * 8];
            #pragma unroll
            for (int f = 0; f < 4; ++f) {
                int vrow = f * 16 + lq;
                const char* vr_ = Vc + vrow * 128;
                bf16x8 vb = *(const bf16x8*)(vr_ + (((kh * 32 + g * 8) * 2) ^ ((vrow & 7) << 4)));
                accO[f] = MFMA16(pa, vb, accO[f]);
            }
        }
        __builtin_amdgcn_s_setprio(0);
    };

    uint4 kr0 = *(const uint4*)(kgb + (size_t)srow * N3);
    uint4 kr1 = *(const uint4*)(kgb + (size_t)(srow + 32) * N3);
    uint4 vr0 = *(const uint4*)(vgb + (size_t)srow * T);
    uint4 vr1 = *(const uint4*)(vgb + (size_t)(srow + 32) * T);
    *(uint4*)((char*)Kt[0] + wb0) = kr0;
    *(uint4*)((char*)Kt[0] + wb1) = kr1;
    *(uint4*)((char*)Vt[0] + wb0) = vr0;
    *(uint4*)((char*)Vt[0] + wb1) = vr1;
    __syncthreads();

    for (int t = 0; t < qt; ++t) {
        int kn = (t + 1) * 64;
        kr0 = *(const uint4*)(kgb + (size_t)(kn + srow) * N3);
        kr1 = *(const uint4*)(kgb + (size_t)(kn + srow + 32) * N3);
        vr0 = *(const uint4*)(vgb + (size_t)srow * T + kn);
        vr1 = *(const uint4*)(vgb + (size_t)(srow + 32) * T + kn);

        do_tile(t & 1, false);

        int nxt = (t & 1) ^ 1;
        *(uint4*)((char*)Kt[nxt] + wb0) = kr0;
        *(uint4*)((char*)Kt[nxt] + wb1) = kr1;
        *(uint4*)((char*)Vt[nxt] + wb0) = vr0;
        *(uint4*)((char*)Vt[nxt] + wb1) = vr1;
        __syncthreads();
    }
    do_tile(qt & 1, true);

    lsum += __shfl_xor(lsum, 16);
    lsum += __shfl_xor(lsum, 32);
    float linv_own = 1.0f / lsum;
    float li[4];
    #pragma unroll
    for (int r = 0; r < 4; ++r) li[r] = __shfl(linv_own, g * 4 + r);

    #pragma unroll
    for (int f = 0; f < 4; ++f)
        #pragma unroll
        for (int r = 0; r < 4; ++r) {
            int trow = qt * 64 + w * 16 + g * 4 + r;
            yb[(size_t)trow * C + h * 64 + f * 16 + lq] = f2bf(accO[f][r] * li[r]);
        }
}

extern "C" void kernel_launch(void* const* d_in, const int* in_sizes, int n_in,
                              void* d_out, int out_size, void* d_ws, size_t ws_size,
                              hipStream_t stream) {
    const float* x       = (const float*)d_in[0];
    const float* cumsc   = (const float*)d_in[1];
    const float* padmask = (const float*)d_in[2];
    const int*   tok     = (const int*)d_in[3];
    const float* w_attn  = (const float*)d_in[4];
    const float* b_attn  = (const float*)d_in[5];
    const float* w_proj  = (const float*)d_in[6];
    const float* b_proj  = (const float*)d_in[7];
    float* out = (float*)d_out;

    float*  pm_tok = (float*)d_ws;                     // 2048
    float2* tab    = (float2*)(pm_tok + 2048);         // 2048*32 float2 (512KB)
    short*  xb     = (short*)(pm_tok + 2048 + 131072); // T*C
    short*  wabT   = xb + (size_t)T * C;               // 3C*C
    short*  wpbT   = wabT + (size_t)N3 * C;            // C*C
    short*  qkvb   = wpbT + (size_t)C * C;             // T*3C (v-section unused)
    short*  vbT    = qkvb + (size_t)T * N3;            // C*T
    short*  yb     = vbT + (size_t)C * T;              // T*C

    pre_kernel<<<3073, 256, 0, stream>>>(x, w_attn, w_proj, tok, padmask,
                                         xb, wabT, wpbT, tab, pm_tok);
    gemm128x64<1><<<dim3(48, 16), 256, 0, stream>>>(xb, wabT, b_attn, qkvb, N3, C,
                                                    tab, cumsc, pm_tok, vbT);
    attn_flash<<<512, 256, 0, stream>>>(qkvb, vbT, yb);
    gemm128x64<0><<<dim3(16, 16), 256, 0, stream>>>(yb, wpbT, b_proj, out, C, C,
                                                    nullptr, nullptr, nullptr, nullptr);
}